// Round 8
// baseline (132.351 us; speedup 1.0000x reference)
//
#include <hip/hip_runtime.h>
#include <hip/hip_bf16.h>
#include <math.h>

// ---------------------------------------------------------------------------
// AdaptivePruner: entropy-gated 1- or 2-level DWT (db4 lowpass) along tokens.
//   x: (32, 4097, 768) f32, cls_attention_map: (32, 4096) f32
//   out0: (32, 2052, 768) f32 = [cls ; lvl==1 ? y1 : pad(y2)]
//   out1: (32, 2052) bool mask (written as 0.0/1.0 f32)
// Round 8: R4 structure (TOUT=16, 2-D grid, 4128 blocks — occupancy is king)
//          + heavy-first batch scheduling: lvl_kernel emits perm[32] with
//          lvl==2 (cascade, ~2.2x work) batches first; dwt maps
//          b = perm[blockIdx.y] so heavy blocks dispatch early and their
//          extra latency is hidden instead of forming a straggler tail.
//          XCD swizzle removed (R7 proved it neutral).
// ---------------------------------------------------------------------------

typedef float f4 __attribute__((ext_vector_type(4)));

#define B_       32
#define NTOK     4097
#define NPATCH   4096
#define D_       768
#define D4_      192    // 768 / 4 channels per float4
#define L1_      2051   // (4096+7)/2, pad (6,6)
#define L2_      1029   // (2051+7)/2, pad (6,7)
#define OUTROWS  2052
#define TOUT     16
#define NTILES   129    // ceil(2051 / 16)

// KERNEL_LO = DEC_LO reversed (JAX conv = correlation, no flip)
__device__ __constant__ float KLO[8] = {
     0.2303778133088965f,
     0.7148465705529157f,
     0.6308807679298589f,
    -0.027983769416859854f,
    -0.18703481171909309f,
     0.030841381835560764f,
     0.0328830116668852f,
    -0.010597401785069032f
};

__device__ __forceinline__ f4 dot8v(const f4 w[8]) {
    f4 a = KLO[0] * w[0];
#pragma unroll
    for (int t = 1; t < 8; ++t) {
        a.x = fmaf(KLO[t], w[t].x, a.x);
        a.y = fmaf(KLO[t], w[t].y, a.y);
        a.z = fmaf(KLO[t], w[t].z, a.z);
        a.w = fmaf(KLO[t], w[t].w, a.w);
    }
    return a;
}

// --- kernel 1: per-batch entropy (double accumulation) ----------------------
__global__ void ent_kernel(const float* __restrict__ att, double* __restrict__ ent) {
    __shared__ double sm[256];
    const int b = blockIdx.x;
    const float* a = att + (size_t)b * NPATCH;
    double acc = 0.0;
    for (int i = threadIdx.x; i < NPATCH; i += 256) {
        double v = (double)a[i];
        acc += v * log2(v + 1e-9);
    }
    sm[threadIdx.x] = acc;
    __syncthreads();
    for (int s = 128; s > 0; s >>= 1) {
        if (threadIdx.x < s) sm[threadIdx.x] += sm[threadIdx.x + s];
        __syncthreads();
    }
    if (threadIdx.x == 0) ent[b] = -sm[0];
}

// --- kernel 2: mean/std(ddof=1) -> level + heavy-first permutation ----------
__global__ void lvl_kernel(const double* __restrict__ ent, int* __restrict__ lvl,
                           int* __restrict__ perm) {
    if (threadIdx.x == 0 && blockIdx.x == 0) {
        double m = 0.0;
        for (int i = 0; i < B_; ++i) m += ent[i];
        m /= (double)B_;
        double v = 0.0;
        for (int i = 0; i < B_; ++i) { double d = ent[i] - m; v += d * d; }
        v /= (double)(B_ - 1);
        double s = sqrt(v);
        double thr0 = m - 1.5 * s;   // lvl==2 iff ent < mean - 1.5*std
        for (int i = 0; i < B_; ++i)
            lvl[i] = (s < 1e-6) ? 1 : ((ent[i] < thr0) ? 2 : 1);
        // heavy (lvl==2) batches first in dispatch order
        int idx = 0;
        for (int i = 0; i < B_; ++i) if (lvl[i] == 2) perm[idx++] = i;
        for (int i = 0; i < B_; ++i) if (lvl[i] == 1) perm[idx++] = i;
    }
}

// --- kernel 3: fused DWT (level 1 or cascaded level 2) + cls row + mask -----
__global__ __launch_bounds__(192) void dwt_kernel(const f4* __restrict__ x,
                                                  const int* __restrict__ lvl,
                                                  const int* __restrict__ perm,
                                                  f4* __restrict__ out,
                                                  float* __restrict__ mask) {
    const int d  = threadIdx.x;                          // float4-channel 0..191
    const int b  = perm[blockIdx.y];                     // heavy batches first
    const int o0 = blockIdx.x * TOUT;
    const int L  = lvl[b];

    const f4* xb = x + (size_t)b * NTOK * D4_ + d;       // row n: xb[n*192]
    f4* ob = out + (size_t)b * OUTROWS * D4_ + d;        // row r: ob[r*192]

    if (blockIdx.x == 0) ob[0] = xb[0];                  // cls token copy

    // fused mask write: rows o0+1 .. o0+TOUT (and row 0 once per batch)
    {
        const int len = (L == 1) ? L1_ : L2_;
        const int o = o0 + d;
        if (d < TOUT && o < L1_)
            mask[(size_t)b * OUTROWS + o + 1] = (o < len) ? 1.0f : 0.0f;
        if (blockIdx.x == 0 && d == TOUT)
            mask[(size_t)b * OUTROWS] = 1.0f;
    }

    const f4 z4 = (f4)(0.0f);
    // xpad[q] = x[b, 1 + (q-6), :] with zero pad outside [0, 4096)
    auto xload = [&](int q) -> f4 {
        const int n = q - 6;
        return (n >= 0 && n < NPATCH) ? xb[(size_t)(n + 1) * D4_] : z4;
    };

    if (L == 1) {
        // y1[o] = sum_k KLO[k] * xpad[2o + k]
        f4 xw[8];
        const int q0 = 2 * o0;
#pragma unroll
        for (int t = 0; t < 8; ++t) xw[t] = xload(q0 + t);
#pragma unroll
        for (int s = 0; s < TOUT; ++s) {
            const int o = o0 + s;
            if (o < L1_) __builtin_nontemporal_store(dot8v(xw), &ob[(size_t)(o + 1) * D4_]);
#pragma unroll
            for (int t = 0; t < 6; ++t) xw[t] = xw[t + 2];
            xw[6] = xload(q0 + 2 * s + 8);
            xw[7] = xload(q0 + 2 * s + 9);
        }
    } else {
        if (o0 >= L2_) {
            // pure zero tail tile
#pragma unroll
            for (int s = 0; s < TOUT; ++s) {
                const int o = o0 + s;
                if (o < L1_) __builtin_nontemporal_store(z4, &ob[(size_t)(o + 1) * D4_]);
            }
            return;
        }
        // cascade: y2[o] = sum_k KLO[k] * y1p[2o + k],
        //          y1p[i] = (0 <= i-6 < 2051) ? y1[i-6] : 0
        int j = 2 * o0 - 6;          // y1 index whose x-window xw currently holds
        f4 xw[8];
#pragma unroll
        for (int t = 0; t < 8; ++t) xw[t] = xload(2 * j + t);

        auto produce = [&]() -> f4 {   // returns y1p[j+6], then advances j
            f4 v = z4;
            if (j >= 0 && j < L1_) v = dot8v(xw);
#pragma unroll
            for (int t = 0; t < 6; ++t) xw[t] = xw[t + 2];
            xw[6] = xload(2 * j + 8);
            xw[7] = xload(2 * j + 9);
            ++j;
            return v;
        };

        f4 yw[8];
#pragma unroll
        for (int t = 0; t < 8; ++t) yw[t] = produce();
#pragma unroll
        for (int s = 0; s < TOUT; ++s) {
            const int o = o0 + s;
            if (o < L1_) {
                f4 v = (o < L2_) ? dot8v(yw) : z4;
                __builtin_nontemporal_store(v, &ob[(size_t)(o + 1) * D4_]);
            }
#pragma unroll
            for (int t = 0; t < 6; ++t) yw[t] = yw[t + 2];
            yw[6] = produce();
            yw[7] = produce();
        }
    }
}

extern "C" void kernel_launch(void* const* d_in, const int* in_sizes, int n_in,
                              void* d_out, int out_size, void* d_ws, size_t ws_size,
                              hipStream_t stream) {
    const float* x   = (const float*)d_in[0];
    const float* att = (const float*)d_in[1];
    float* out  = (float*)d_out;
    float* mask = out + (size_t)B_ * OUTROWS * D_;

    double* ent = (double*)d_ws;
    int*    lvl = (int*)((char*)d_ws + B_ * sizeof(double));
    int*    perm = lvl + B_;

    ent_kernel<<<B_, 256, 0, stream>>>(att, ent);
    lvl_kernel<<<1, 64, 0, stream>>>(ent, lvl, perm);

    dim3 grid(NTILES, B_, 1);
    dwt_kernel<<<grid, 192, 0, stream>>>((const f4*)x, lvl, perm, (f4*)out, mask);
}

// Round 9
// 130.406 us; speedup vs baseline: 1.0149x; 1.0149x over previous
//
#include <hip/hip_runtime.h>
#include <hip/hip_bf16.h>
#include <math.h>

// ---------------------------------------------------------------------------
// AdaptivePruner: entropy-gated 1- or 2-level DWT (db4 lowpass) along tokens.
//   x: (32, 4097, 768) f32, cls_attention_map: (32, 4096) f32
//   out0: (32, 2052, 768) f32 = [cls ; lvl==1 ? y1 : pad(y2)]
//   out1: (32, 2052) bool mask (written as 0.0/1.0 f32)
// Round 9: exact R7 structure (TOUT=16, 4128 blocks, XCD swizzle) + ONE
//          change: __launch_bounds__(192, 4) to force <=128 VGPR so >=4
//          waves/SIMD are resident. Theory: the fully-unrolled window pushed
//          VGPR past 128, capping occupancy at 2-3 waves/SIMD — explaining
//          the strong block-count sensitivity (TLP-starved latency) while
//          swizzle (R7) and heavy-first (R8) were both null.
// ---------------------------------------------------------------------------

typedef float f4 __attribute__((ext_vector_type(4)));

#define B_       32
#define NTOK     4097
#define NPATCH   4096
#define D_       768
#define D4_      192    // 768 / 4 channels per float4
#define L1_      2051   // (4096+7)/2, pad (6,6)
#define L2_      1029   // (2051+7)/2, pad (6,7)
#define OUTROWS  2052
#define TOUT     16
#define NTILES   129    // ceil(2051 / 16)
#define NWG      (B_ * NTILES)   // 4128, divisible by 8

// KERNEL_LO = DEC_LO reversed (JAX conv = correlation, no flip)
__device__ __constant__ float KLO[8] = {
     0.2303778133088965f,
     0.7148465705529157f,
     0.6308807679298589f,
    -0.027983769416859854f,
    -0.18703481171909309f,
     0.030841381835560764f,
     0.0328830116668852f,
    -0.010597401785069032f
};

__device__ __forceinline__ f4 dot8v(const f4 w[8]) {
    f4 a = KLO[0] * w[0];
#pragma unroll
    for (int t = 1; t < 8; ++t) {
        a.x = fmaf(KLO[t], w[t].x, a.x);
        a.y = fmaf(KLO[t], w[t].y, a.y);
        a.z = fmaf(KLO[t], w[t].z, a.z);
        a.w = fmaf(KLO[t], w[t].w, a.w);
    }
    return a;
}

// --- kernel 1: per-batch entropy (double accumulation) ----------------------
__global__ void ent_kernel(const float* __restrict__ att, double* __restrict__ ent) {
    __shared__ double sm[256];
    const int b = blockIdx.x;
    const float* a = att + (size_t)b * NPATCH;
    double acc = 0.0;
    for (int i = threadIdx.x; i < NPATCH; i += 256) {
        double v = (double)a[i];
        acc += v * log2(v + 1e-9);
    }
    sm[threadIdx.x] = acc;
    __syncthreads();
    for (int s = 128; s > 0; s >>= 1) {
        if (threadIdx.x < s) sm[threadIdx.x] += sm[threadIdx.x + s];
        __syncthreads();
    }
    if (threadIdx.x == 0) ent[b] = -sm[0];
}

// --- kernel 2: mean/std(ddof=1) -> per-batch level --------------------------
__global__ void lvl_kernel(const double* __restrict__ ent, int* __restrict__ lvl) {
    if (threadIdx.x == 0 && blockIdx.x == 0) {
        double m = 0.0;
        for (int i = 0; i < B_; ++i) m += ent[i];
        m /= (double)B_;
        double v = 0.0;
        for (int i = 0; i < B_; ++i) { double d = ent[i] - m; v += d * d; }
        v /= (double)(B_ - 1);
        double s = sqrt(v);
        double thr0 = m - 1.5 * s;   // lvl==2 iff ent < mean - 1.5*std
        for (int i = 0; i < B_; ++i)
            lvl[i] = (s < 1e-6) ? 1 : ((ent[i] < thr0) ? 2 : 1);
    }
}

// --- kernel 3: fused DWT (level 1 or cascaded level 2) + cls row + mask -----
__global__ __launch_bounds__(192, 4) void dwt_kernel(const f4* __restrict__ x,
                                                     const int* __restrict__ lvl,
                                                     f4* __restrict__ out,
                                                     float* __restrict__ mask) {
    // Bijective XCD swizzle (NWG % 8 == 0).
    const int bid  = blockIdx.x;
    const int lid  = (bid & 7) * (NWG / 8) + (bid >> 3);
    const int b    = lid / NTILES;
    const int tile = lid % NTILES;
    const int o0   = tile * TOUT;

    const int d  = threadIdx.x;                          // float4-channel 0..191
    const int L  = lvl[b];

    const f4* xb = x + (size_t)b * NTOK * D4_ + d;       // row n: xb[n*192]
    f4* ob = out + (size_t)b * OUTROWS * D4_ + d;        // row r: ob[r*192]

    if (tile == 0) ob[0] = xb[0];                        // cls token copy

    // fused mask write: rows o0+1 .. o0+TOUT (and row 0 once per batch)
    {
        const int len = (L == 1) ? L1_ : L2_;
        const int o = o0 + d;
        if (d < TOUT && o < L1_)
            mask[(size_t)b * OUTROWS + o + 1] = (o < len) ? 1.0f : 0.0f;
        if (tile == 0 && d == TOUT)
            mask[(size_t)b * OUTROWS] = 1.0f;
    }

    const f4 z4 = (f4)(0.0f);
    // xpad[q] = x[b, 1 + (q-6), :] with zero pad outside [0, 4096)
    auto xload = [&](int q) -> f4 {
        const int n = q - 6;
        return (n >= 0 && n < NPATCH) ? xb[(size_t)(n + 1) * D4_] : z4;
    };

    if (L == 1) {
        // y1[o] = sum_k KLO[k] * xpad[2o + k]
        f4 xw[8];
        const int q0 = 2 * o0;
#pragma unroll
        for (int t = 0; t < 8; ++t) xw[t] = xload(q0 + t);
#pragma unroll
        for (int s = 0; s < TOUT; ++s) {
            const int o = o0 + s;
            if (o < L1_) __builtin_nontemporal_store(dot8v(xw), &ob[(size_t)(o + 1) * D4_]);
#pragma unroll
            for (int t = 0; t < 6; ++t) xw[t] = xw[t + 2];
            xw[6] = xload(q0 + 2 * s + 8);
            xw[7] = xload(q0 + 2 * s + 9);
        }
    } else {
        if (o0 >= L2_) {
            // pure zero tail tile
#pragma unroll
            for (int s = 0; s < TOUT; ++s) {
                const int o = o0 + s;
                if (o < L1_) __builtin_nontemporal_store(z4, &ob[(size_t)(o + 1) * D4_]);
            }
            return;
        }
        // cascade: y2[o] = sum_k KLO[k] * y1p[2o + k],
        //          y1p[i] = (0 <= i-6 < 2051) ? y1[i-6] : 0
        int j = 2 * o0 - 6;          // y1 index whose x-window xw currently holds
        f4 xw[8];
#pragma unroll
        for (int t = 0; t < 8; ++t) xw[t] = xload(2 * j + t);

        auto produce = [&]() -> f4 {   // returns y1p[j+6], then advances j
            f4 v = z4;
            if (j >= 0 && j < L1_) v = dot8v(xw);
#pragma unroll
            for (int t = 0; t < 6; ++t) xw[t] = xw[t + 2];
            xw[6] = xload(2 * j + 8);
            xw[7] = xload(2 * j + 9);
            ++j;
            return v;
        };

        f4 yw[8];
#pragma unroll
        for (int t = 0; t < 8; ++t) yw[t] = produce();
#pragma unroll
        for (int s = 0; s < TOUT; ++s) {
            const int o = o0 + s;
            if (o < L1_) {
                f4 v = (o < L2_) ? dot8v(yw) : z4;
                __builtin_nontemporal_store(v, &ob[(size_t)(o + 1) * D4_]);
            }
#pragma unroll
            for (int t = 0; t < 6; ++t) yw[t] = yw[t + 2];
            yw[6] = produce();
            yw[7] = produce();
        }
    }
}

extern "C" void kernel_launch(void* const* d_in, const int* in_sizes, int n_in,
                              void* d_out, int out_size, void* d_ws, size_t ws_size,
                              hipStream_t stream) {
    const float* x   = (const float*)d_in[0];
    const float* att = (const float*)d_in[1];
    float* out  = (float*)d_out;
    float* mask = out + (size_t)B_ * OUTROWS * D_;

    double* ent = (double*)d_ws;
    int*    lvl = (int*)((char*)d_ws + B_ * sizeof(double));

    ent_kernel<<<B_, 256, 0, stream>>>(att, ent);
    lvl_kernel<<<1, 64, 0, stream>>>(ent, lvl);

    dwt_kernel<<<NWG, 192, 0, stream>>>((const f4*)x, lvl, (f4*)out, mask);
}

// Round 10
// 126.172 us; speedup vs baseline: 1.0490x; 1.0336x over previous
//
#include <hip/hip_runtime.h>
#include <hip/hip_bf16.h>
#include <math.h>

// ---------------------------------------------------------------------------
// AdaptivePruner: entropy-gated 1- or 2-level DWT (db4 lowpass) along tokens.
//   x: (32, 4097, 768) f32, cls_attention_map: (32, 4096) f32
//   out0: (32, 2052, 768) f32 = [cls ; lvl==1 ? y1 : pad(y2)]
//   out1: (32, 2052) bool mask (written as 0.0/1.0 f32)
// Round 10: (a) lvl_kernel removed — each dwt block recomputes mean/std/lvl
//           from ent[32] redundantly (256 B, uniform scalar; kills one graph
//           node + gap). (b) guard-free interior fast paths: tiles whose
//           loads/stores are provably in-bounds run a single straight-line
//           basic block (no store guards, no load clamps) so the compiler
//           can hoist/pipeline all loads -> per-wave ILP, less TLP reliance.
// ---------------------------------------------------------------------------

typedef float f4 __attribute__((ext_vector_type(4)));

#define B_       32
#define NTOK     4097
#define NPATCH   4096
#define D_       768
#define D4_      192    // 768 / 4 channels per float4
#define L1_      2051   // (4096+7)/2, pad (6,6)
#define L2_      1029   // (2051+7)/2, pad (6,7)
#define OUTROWS  2052
#define TOUT     16
#define NTILES   129    // ceil(2051 / 16)
#define NWG      (B_ * NTILES)   // 4128, divisible by 8

// KERNEL_LO = DEC_LO reversed (JAX conv = correlation, no flip)
__device__ __constant__ float KLO[8] = {
     0.2303778133088965f,
     0.7148465705529157f,
     0.6308807679298589f,
    -0.027983769416859854f,
    -0.18703481171909309f,
     0.030841381835560764f,
     0.0328830116668852f,
    -0.010597401785069032f
};

__device__ __forceinline__ f4 dot8v(const f4 w[8]) {
    f4 a = KLO[0] * w[0];
#pragma unroll
    for (int t = 1; t < 8; ++t) {
        a.x = fmaf(KLO[t], w[t].x, a.x);
        a.y = fmaf(KLO[t], w[t].y, a.y);
        a.z = fmaf(KLO[t], w[t].z, a.z);
        a.w = fmaf(KLO[t], w[t].w, a.w);
    }
    return a;
}

// --- kernel 1: per-batch entropy (double accumulation) ----------------------
__global__ void ent_kernel(const float* __restrict__ att, double* __restrict__ ent) {
    __shared__ double sm[256];
    const int b = blockIdx.x;
    const float* a = att + (size_t)b * NPATCH;
    double acc = 0.0;
    for (int i = threadIdx.x; i < NPATCH; i += 256) {
        double v = (double)a[i];
        acc += v * log2(v + 1e-9);
    }
    sm[threadIdx.x] = acc;
    __syncthreads();
    for (int s = 128; s > 0; s >>= 1) {
        if (threadIdx.x < s) sm[threadIdx.x] += sm[threadIdx.x + s];
        __syncthreads();
    }
    if (threadIdx.x == 0) ent[b] = -sm[0];
}

// --- kernel 2: fused DWT + inline level decision + cls row + mask -----------
__global__ __launch_bounds__(192) void dwt_kernel(const f4* __restrict__ x,
                                                  const double* __restrict__ ent,
                                                  f4* __restrict__ out,
                                                  float* __restrict__ mask) {
    // Bijective XCD swizzle (NWG % 8 == 0).
    const int bid  = blockIdx.x;
    const int lid  = (bid & 7) * (NWG / 8) + (bid >> 3);
    const int b    = lid / NTILES;
    const int tile = lid % NTILES;
    const int o0   = tile * TOUT;
    const int d    = threadIdx.x;                        // float4-channel 0..191

    // inline stats (uniform, redundant per thread — ~100 double ops, L2-hit)
    double m = 0.0;
    for (int i = 0; i < B_; ++i) m += ent[i];
    m *= (1.0 / B_);
    double v = 0.0;
    for (int i = 0; i < B_; ++i) { double dd = ent[i] - m; v += dd * dd; }
    v *= (1.0 / (B_ - 1));
    const double sd = sqrt(v);
    const int L = (sd < 1e-6) ? 1 : ((ent[b] < m - 1.5 * sd) ? 2 : 1);

    const f4* xb = x + (size_t)b * NTOK * D4_ + d;       // row n: xb[n*192]
    f4* ob = out + (size_t)b * OUTROWS * D4_ + d;        // row r: ob[r*192]

    if (tile == 0) ob[0] = xb[0];                        // cls token copy

    // fused mask write: rows o0+1 .. o0+TOUT (and row 0 once per batch)
    {
        const int len = (L == 1) ? L1_ : L2_;
        const int o = o0 + d;
        if (d < TOUT && o < L1_)
            mask[(size_t)b * OUTROWS + o + 1] = (o < len) ? 1.0f : 0.0f;
        if (tile == 0 && d == TOUT)
            mask[(size_t)b * OUTROWS] = 1.0f;
    }

    const f4 z4 = (f4)(0.0f);
    // xpad[q] = x[b, 1 + (q-6), :] with zero pad outside [0, 4096)
    auto xload = [&](int q) -> f4 {
        const int n = q - 6;
        return (n >= 0 && n < NPATCH) ? xb[(size_t)(n + 1) * D4_] : z4;
    };
    // unguarded row read for interior tiles: row = (q-6)+1
    auto xrow = [&](int q) -> f4 {
        return xb[(size_t)(q - 5) * D4_];
    };

    if (L == 1) {
        const int q0 = 2 * o0;
        if (o0 >= TOUT && o0 <= 2016) {
            // ---- interior fast path: all loads in [0,4096), all 16 stores valid
            f4 xw[8];
#pragma unroll
            for (int t = 0; t < 8; ++t) xw[t] = xrow(q0 + t);
#pragma unroll
            for (int s = 0; s < TOUT; ++s) {
                __builtin_nontemporal_store(dot8v(xw), &ob[(size_t)(o0 + s + 1) * D4_]);
#pragma unroll
                for (int t = 0; t < 6; ++t) xw[t] = xw[t + 2];
                xw[6] = xrow(q0 + 2 * s + 8);
                xw[7] = xrow(q0 + 2 * s + 9);
            }
        } else {
            // ---- guarded boundary path
            f4 xw[8];
#pragma unroll
            for (int t = 0; t < 8; ++t) xw[t] = xload(q0 + t);
#pragma unroll
            for (int s = 0; s < TOUT; ++s) {
                const int o = o0 + s;
                if (o < L1_) __builtin_nontemporal_store(dot8v(xw), &ob[(size_t)(o + 1) * D4_]);
#pragma unroll
                for (int t = 0; t < 6; ++t) xw[t] = xw[t + 2];
                xw[6] = xload(q0 + 2 * s + 8);
                xw[7] = xload(q0 + 2 * s + 9);
            }
        }
    } else {
        if (o0 >= L2_) {
            // pure zero tail tile
#pragma unroll
            for (int s = 0; s < TOUT; ++s) {
                const int o = o0 + s;
                if (o < L1_) __builtin_nontemporal_store(z4, &ob[(size_t)(o + 1) * D4_]);
            }
            return;
        }
        if (o0 >= TOUT && o0 <= 992) {
            // ---- interior fast path: j in [0,2051), x rows in [0,4096), stores < L2_
            int j = 2 * o0 - 6;
            f4 xw[8];
#pragma unroll
            for (int t = 0; t < 8; ++t) xw[t] = xrow(2 * j + t);

            auto produceF = [&]() -> f4 {
                f4 vv = dot8v(xw);
#pragma unroll
                for (int t = 0; t < 6; ++t) xw[t] = xw[t + 2];
                xw[6] = xrow(2 * j + 8);
                xw[7] = xrow(2 * j + 9);
                ++j;
                return vv;
            };

            f4 yw[8];
#pragma unroll
            for (int t = 0; t < 8; ++t) yw[t] = produceF();
#pragma unroll
            for (int s = 0; s < TOUT; ++s) {
                __builtin_nontemporal_store(dot8v(yw), &ob[(size_t)(o0 + s + 1) * D4_]);
#pragma unroll
                for (int t = 0; t < 6; ++t) yw[t] = yw[t + 2];
                yw[6] = produceF();
                yw[7] = produceF();
            }
        } else {
            // ---- guarded boundary path
            int j = 2 * o0 - 6;
            f4 xw[8];
#pragma unroll
            for (int t = 0; t < 8; ++t) xw[t] = xload(2 * j + t);

            auto produce = [&]() -> f4 {
                f4 vv = z4;
                if (j >= 0 && j < L1_) vv = dot8v(xw);
#pragma unroll
                for (int t = 0; t < 6; ++t) xw[t] = xw[t + 2];
                xw[6] = xload(2 * j + 8);
                xw[7] = xload(2 * j + 9);
                ++j;
                return vv;
            };

            f4 yw[8];
#pragma unroll
            for (int t = 0; t < 8; ++t) yw[t] = produce();
#pragma unroll
            for (int s = 0; s < TOUT; ++s) {
                const int o = o0 + s;
                if (o < L1_) {
                    f4 vv = (o < L2_) ? dot8v(yw) : z4;
                    __builtin_nontemporal_store(vv, &ob[(size_t)(o + 1) * D4_]);
                }
#pragma unroll
                for (int t = 0; t < 6; ++t) yw[t] = yw[t + 2];
                yw[6] = produce();
                yw[7] = produce();
            }
        }
    }
}

extern "C" void kernel_launch(void* const* d_in, const int* in_sizes, int n_in,
                              void* d_out, int out_size, void* d_ws, size_t ws_size,
                              hipStream_t stream) {
    const float* x   = (const float*)d_in[0];
    const float* att = (const float*)d_in[1];
    float* out  = (float*)d_out;
    float* mask = out + (size_t)B_ * OUTROWS * D_;

    double* ent = (double*)d_ws;

    ent_kernel<<<B_, 256, 0, stream>>>(att, ent);
    dwt_kernel<<<NWG, 192, 0, stream>>>((const f4*)x, ent, (f4*)out, mask);
}

// Round 11
// 125.093 us; speedup vs baseline: 1.0580x; 1.0086x over previous
//
#include <hip/hip_runtime.h>
#include <hip/hip_bf16.h>
#include <math.h>

// ---------------------------------------------------------------------------
// AdaptivePruner: entropy-gated 1- or 2-level DWT (db4 lowpass) along tokens.
//   x: (32, 4097, 768) f32, cls_attention_map: (32, 4096) f32
//   out0: (32, 2052, 768) f32 = [cls ; lvl==1 ? y1 : pad(y2)]
//   out1: (32, 2052) bool mask (written as 0.0/1.0 f32)
// Round 11: R10 + prologue restructure. The per-block stats recompute (64
//           uniform double loads + ~100 dops + sqrt) sat BEFORE the branch on
//           L, so no x-load could issue until it resolved. Now the L1 window
//           (correct for ~93% of blocks) is preloaded FIRST, stats overlap
//           the loads, and cls/mask stores move to the epilogue. L==2 blocks
//           discard the preload (~1.5% extra fetch).
// ---------------------------------------------------------------------------

typedef float f4 __attribute__((ext_vector_type(4)));

#define B_       32
#define NTOK     4097
#define NPATCH   4096
#define D_       768
#define D4_      192    // 768 / 4 channels per float4
#define L1_      2051   // (4096+7)/2, pad (6,6)
#define L2_      1029   // (2051+7)/2, pad (6,7)
#define OUTROWS  2052
#define TOUT     16
#define NTILES   129    // ceil(2051 / 16)
#define NWG      (B_ * NTILES)   // 4128, divisible by 8

// KERNEL_LO = DEC_LO reversed (JAX conv = correlation, no flip)
__device__ __constant__ float KLO[8] = {
     0.2303778133088965f,
     0.7148465705529157f,
     0.6308807679298589f,
    -0.027983769416859854f,
    -0.18703481171909309f,
     0.030841381835560764f,
     0.0328830116668852f,
    -0.010597401785069032f
};

__device__ __forceinline__ f4 dot8v(const f4 w[8]) {
    f4 a = KLO[0] * w[0];
#pragma unroll
    for (int t = 1; t < 8; ++t) {
        a.x = fmaf(KLO[t], w[t].x, a.x);
        a.y = fmaf(KLO[t], w[t].y, a.y);
        a.z = fmaf(KLO[t], w[t].z, a.z);
        a.w = fmaf(KLO[t], w[t].w, a.w);
    }
    return a;
}

// --- kernel 1: per-batch entropy (double accumulation) ----------------------
__global__ void ent_kernel(const float* __restrict__ att, double* __restrict__ ent) {
    __shared__ double sm[256];
    const int b = blockIdx.x;
    const float* a = att + (size_t)b * NPATCH;
    double acc = 0.0;
    for (int i = threadIdx.x; i < NPATCH; i += 256) {
        double v = (double)a[i];
        acc += v * log2(v + 1e-9);
    }
    sm[threadIdx.x] = acc;
    __syncthreads();
    for (int s = 128; s > 0; s >>= 1) {
        if (threadIdx.x < s) sm[threadIdx.x] += sm[threadIdx.x + s];
        __syncthreads();
    }
    if (threadIdx.x == 0) ent[b] = -sm[0];
}

// --- kernel 2: fused DWT + inline level decision + cls row + mask -----------
__global__ __launch_bounds__(192) void dwt_kernel(const f4* __restrict__ x,
                                                  const double* __restrict__ ent,
                                                  f4* __restrict__ out,
                                                  float* __restrict__ mask) {
    // Bijective XCD swizzle (NWG % 8 == 0).
    const int bid  = blockIdx.x;
    const int lid  = (bid & 7) * (NWG / 8) + (bid >> 3);
    const int b    = lid / NTILES;
    const int tile = lid % NTILES;
    const int o0   = tile * TOUT;
    const int d    = threadIdx.x;                        // float4-channel 0..191

    const f4* xb = x + (size_t)b * NTOK * D4_ + d;       // row n: xb[n*192]
    f4* ob = out + (size_t)b * OUTROWS * D4_ + d;        // row r: ob[r*192]

    const f4 z4 = (f4)(0.0f);
    // xpad[q] = x[b, 1 + (q-6), :] with zero pad outside [0, 4096)
    auto xload = [&](int q) -> f4 {
        const int n = q - 6;
        return (n >= 0 && n < NPATCH) ? xb[(size_t)(n + 1) * D4_] : z4;
    };
    // unguarded row read for interior tiles: row = (q-6)+1
    auto xrow = [&](int q) -> f4 {
        return xb[(size_t)(q - 5) * D4_];
    };

    const bool interior = (o0 >= TOUT && o0 <= 2016);
    const int q0 = 2 * o0;

    // ---- issue the L1 window loads FIRST (correct for ~93% of blocks); the
    //      stats below overlap these loads instead of blocking them.
    f4 xw[8];
    if (interior) {
#pragma unroll
        for (int t = 0; t < 8; ++t) xw[t] = xrow(q0 + t);
    } else {
#pragma unroll
        for (int t = 0; t < 8; ++t) xw[t] = xload(q0 + t);
    }

    // ---- inline stats (uniform, redundant per thread; overlaps loads above)
    double m = 0.0;
    for (int i = 0; i < B_; ++i) m += ent[i];
    m *= (1.0 / B_);
    double v = 0.0;
    for (int i = 0; i < B_; ++i) { double dd = ent[i] - m; v += dd * dd; }
    v *= (1.0 / (B_ - 1));
    const double sd = sqrt(v);
    const int L = (sd < 1e-6) ? 1 : ((ent[b] < m - 1.5 * sd) ? 2 : 1);

    if (L == 1) {
        if (interior) {
            // ---- interior fast path: all loads in-bounds, all 16 stores valid
#pragma unroll
            for (int s = 0; s < TOUT; ++s) {
                __builtin_nontemporal_store(dot8v(xw), &ob[(size_t)(o0 + s + 1) * D4_]);
#pragma unroll
                for (int t = 0; t < 6; ++t) xw[t] = xw[t + 2];
                xw[6] = xrow(q0 + 2 * s + 8);
                xw[7] = xrow(q0 + 2 * s + 9);
            }
        } else {
            // ---- guarded boundary path
#pragma unroll
            for (int s = 0; s < TOUT; ++s) {
                const int o = o0 + s;
                if (o < L1_) __builtin_nontemporal_store(dot8v(xw), &ob[(size_t)(o + 1) * D4_]);
#pragma unroll
                for (int t = 0; t < 6; ++t) xw[t] = xw[t + 2];
                xw[6] = xload(q0 + 2 * s + 8);
                xw[7] = xload(q0 + 2 * s + 9);
            }
        }
    } else {
        if (o0 >= L2_) {
            // pure zero tail tile
#pragma unroll
            for (int s = 0; s < TOUT; ++s) {
                const int o = o0 + s;
                if (o < L1_) __builtin_nontemporal_store(z4, &ob[(size_t)(o + 1) * D4_]);
            }
        } else if (o0 >= TOUT && o0 <= 992) {
            // ---- interior fast path: j in [0,2051), x rows in [0,4096)
            int j = 2 * o0 - 6;
#pragma unroll
            for (int t = 0; t < 8; ++t) xw[t] = xrow(2 * j + t);

            auto produceF = [&]() -> f4 {
                f4 vv = dot8v(xw);
#pragma unroll
                for (int t = 0; t < 6; ++t) xw[t] = xw[t + 2];
                xw[6] = xrow(2 * j + 8);
                xw[7] = xrow(2 * j + 9);
                ++j;
                return vv;
            };

            f4 yw[8];
#pragma unroll
            for (int t = 0; t < 8; ++t) yw[t] = produceF();
#pragma unroll
            for (int s = 0; s < TOUT; ++s) {
                __builtin_nontemporal_store(dot8v(yw), &ob[(size_t)(o0 + s + 1) * D4_]);
#pragma unroll
                for (int t = 0; t < 6; ++t) yw[t] = yw[t + 2];
                yw[6] = produceF();
                yw[7] = produceF();
            }
        } else {
            // ---- guarded boundary path
            int j = 2 * o0 - 6;
#pragma unroll
            for (int t = 0; t < 8; ++t) xw[t] = xload(2 * j + t);

            auto produce = [&]() -> f4 {
                f4 vv = z4;
                if (j >= 0 && j < L1_) vv = dot8v(xw);
#pragma unroll
                for (int t = 0; t < 6; ++t) xw[t] = xw[t + 2];
                xw[6] = xload(2 * j + 8);
                xw[7] = xload(2 * j + 9);
                ++j;
                return vv;
            };

            f4 yw[8];
#pragma unroll
            for (int t = 0; t < 8; ++t) yw[t] = produce();
#pragma unroll
            for (int s = 0; s < TOUT; ++s) {
                const int o = o0 + s;
                if (o < L1_) {
                    f4 vv = (o < L2_) ? dot8v(yw) : z4;
                    __builtin_nontemporal_store(vv, &ob[(size_t)(o + 1) * D4_]);
                }
#pragma unroll
                for (int t = 0; t < 6; ++t) yw[t] = yw[t + 2];
                yw[6] = produce();
                yw[7] = produce();
            }
        }
    }

    // ---- epilogue: cls row + mask (off the load-issue critical path)
    if (tile == 0) ob[0] = xb[0];
    {
        const int len = (L == 1) ? L1_ : L2_;
        const int o = o0 + d;
        if (d < TOUT && o < L1_)
            mask[(size_t)b * OUTROWS + o + 1] = (o < len) ? 1.0f : 0.0f;
        if (tile == 0 && d == TOUT)
            mask[(size_t)b * OUTROWS] = 1.0f;
    }
}

extern "C" void kernel_launch(void* const* d_in, const int* in_sizes, int n_in,
                              void* d_out, int out_size, void* d_ws, size_t ws_size,
                              hipStream_t stream) {
    const float* x   = (const float*)d_in[0];
    const float* att = (const float*)d_in[1];
    float* out  = (float*)d_out;
    float* mask = out + (size_t)B_ * OUTROWS * D_;

    double* ent = (double*)d_ws;

    ent_kernel<<<B_, 256, 0, stream>>>(att, ent);
    dwt_kernel<<<NWG, 192, 0, stream>>>((const f4*)x, ent, (f4*)out, mask);
}